// Round 8
// baseline (1454.804 us; speedup 1.0000x reference)
//
#include <hip/hip_runtime.h>
#include <hip/hip_bf16.h>

// Problem constants (from setup_inputs)
#define NROWS 131072
#define DIN   512
#define HDIM  128
#define EDIM  32
#define KCODES 512

// ---- DIAGNOSTIC ROUND: in-kernel repetition to crack the rocprof top-5
// visibility threshold (~157us fillBuffer rows). Work is idempotent; rep>0
// accumulators go to dummy scratch. Outputs bit-identical to REPS=1.
#define REPS_G 5
#define REPS_E 8
#define REPS_R 5

typedef unsigned short ushort_t;
typedef unsigned int   uint_t;
typedef float f32x4 __attribute__((ext_vector_type(4)));
typedef short s16x8 __attribute__((ext_vector_type(8)));

// ---------- bf16 helpers ----------
__device__ __forceinline__ float bflo(uint_t u) {
  union { uint_t u; float f; } x; x.u = u << 16; return x.f;
}
__device__ __forceinline__ float bfhi(uint_t u) {
  union { uint_t u; float f; } x; x.u = u & 0xffff0000u; return x.f;
}
__device__ __forceinline__ ushort_t f2bf(float f) {   // RNE (off hot path)
  union { float f; uint_t u; } x; x.f = f;
  uint_t u = x.u;
  return (ushort_t)((u + 0x7fffu + ((u >> 16) & 1u)) >> 16);
}
// pack-truncate 2 fp32 -> (bf16(hi)<<16)|bf16(lo) in ONE v_perm_b32.
__device__ __forceinline__ uint_t pk2(float lo, float hi) {
  return __builtin_amdgcn_perm(__float_as_uint(hi), __float_as_uint(lo), 0x07060302u);
}

// ---------------------------------------------------------------------------
// k_prep (unchanged from round 7)
// ---------------------------------------------------------------------------
__global__ __launch_bounds__(256) void k_prep(
    const float* __restrict__ W1, const float* __restrict__ W2,
    const float* __restrict__ CB, const float* __restrict__ dW1,
    const float* __restrict__ db1,
    ushort_t* __restrict__ W1t, ushort_t* __restrict__ W2t,
    ushort_t* __restrict__ CBb, float* __restrict__ cn,
    float* __restrict__ T, float* __restrict__ accz)
{
  int gid = blockIdx.x * 256 + threadIdx.x;   // 0..65535
  {
    W1t[gid] = f2bf(W1[(gid & 511) * 128 + (gid >> 9)]);
  }
  {
    int k = gid >> 7, j = gid & 127;          // T[k][j], 512x128
    float acc = db1[j];
#pragma unroll
    for (int e = 0; e < EDIM; ++e) acc += CB[k * EDIM + e] * dW1[e * HDIM + j];
    T[gid] = acc;
  }
  if (gid < 16384) CBb[gid] = f2bf(CB[gid]);
  if (gid < 4096) {
    int e = gid >> 7, k = gid & 127;
    W2t[gid] = f2bf(W2[k * 32 + e]);
  }
  if (gid < 512) {
    float s = 0.f;
#pragma unroll
    for (int e = 0; e < EDIM; ++e) { float c = CB[gid * EDIM + e]; s += c * c; }
    cn[gid] = s;
  }
  if (gid < 1024) accz[gid] = 0.f;
}

// ---------------------------------------------------------------------------
// K1: identical structure to round 7, wrapped in REPS_G loop.
// ---------------------------------------------------------------------------
__global__ __launch_bounds__(256, 4) void k_gemm1(
    const float* __restrict__ X, const ushort_t* __restrict__ W1t,
    const float* __restrict__ b1, ushort_t* __restrict__ H1,
    float* __restrict__ colsum, float* __restrict__ colsumsq,
    float* __restrict__ dumA, float* __restrict__ dumB)
{
  __shared__ float Af[2][128 * 32];
  __shared__ float lsum[128], lssq[128];
  const int tid = threadIdx.x;
  const int lane = tid & 63;
  const int wid = tid >> 6;
  const int wr = wid >> 1, wc = wid & 1;
  const size_t row0 = (size_t)blockIdx.x * 128;

  const int lr = lane & 15;
  const int lk = lane >> 4;
  const int sub = lane >> 3;
  const int q8  = lane & 7;

  int bofs[4];
#pragma unroll
  for (int nf = 0; nf < 4; ++nf)
    bofs[nf] = (wc * 64 + nf * 16 + lr) * 512 + lk * 8;

  int aofs[4][2];
#pragma unroll
  for (int mf = 0; mf < 4; ++mf) {
    int r = wr * 64 + mf * 16 + lr;
#pragma unroll
    for (int hq = 0; hq < 2; ++hq)
      aofs[mf][hq] = r * 32 + (((2 * lk + hq) ^ (r & 7)) << 2);
  }

  typedef __attribute__((address_space(1))) const void gv_t;
  typedef __attribute__((address_space(3))) void lv_t;

  for (int rep = 0; rep < REPS_G; ++rep) {
    float* csT = (rep == 0) ? colsum : dumA;
    float* cqT = (rep == 0) ? colsumsq : dumB;
    if (tid < 128) { lsum[tid] = 0.f; lssq[tid] = 0.f; }

    f32x4 acc[4][4];
#pragma unroll
    for (int i = 0; i < 4; ++i)
#pragma unroll
      for (int j = 0; j < 4; ++j) acc[i][j] = (f32x4)(0.f);

    // prologue DMA tile 0 -> buf 0
#pragma unroll
    for (int i = 0; i < 4; ++i) {
      int r0 = (wid * 4 + i) * 8;
      int r = r0 + sub;
      const float* src = X + (row0 + r) * 512 + ((q8 ^ (r & 7)) << 2);
      __builtin_amdgcn_global_load_lds((gv_t*)src, (lv_t*)&Af[0][r0 * 32], 16, 0, 0);
    }
    __syncthreads();

    for (int it = 0; it < 16; ++it) {
      const int cur = it & 1;
      if (it < 15) {
        const int kc2 = (it + 1) * 32;
#pragma unroll
        for (int i = 0; i < 4; ++i) {
          int r0 = (wid * 4 + i) * 8;
          int r = r0 + sub;
          const float* src = X + (row0 + r) * 512 + kc2 + ((q8 ^ (r & 7)) << 2);
          __builtin_amdgcn_global_load_lds((gv_t*)src, (lv_t*)&Af[cur ^ 1][r0 * 32], 16, 0, 0);
        }
      }
      s16x8 bfrag[4];
#pragma unroll
      for (int nf = 0; nf < 4; ++nf)
        bfrag[nf] = *(const s16x8*)(W1t + bofs[nf] + it * 32);
      s16x8 afrag[4];
#pragma unroll
      for (int mf = 0; mf < 4; ++mf) {
        f32x4 qa = *(const f32x4*)(&Af[cur][aofs[mf][0]]);
        f32x4 qb = *(const f32x4*)(&Af[cur][aofs[mf][1]]);
        union { s16x8 v; uint_t u[4]; } t;
        t.u[0] = pk2(qa[0], qa[1]);
        t.u[1] = pk2(qa[2], qa[3]);
        t.u[2] = pk2(qb[0], qb[1]);
        t.u[3] = pk2(qb[2], qb[3]);
        afrag[mf] = t.v;
      }
#pragma unroll
      for (int mf = 0; mf < 4; ++mf)
#pragma unroll
        for (int nf = 0; nf < 4; ++nf)
          acc[mf][nf] = __builtin_amdgcn_mfma_f32_16x16x32_bf16(
              afrag[mf], bfrag[nf], acc[mf][nf], 0, 0, 0);
      __syncthreads();
    }

    // epilogue
    float bv[4]; int col[4];
#pragma unroll
    for (int nf = 0; nf < 4; ++nf) {
      col[nf] = wc * 64 + nf * 16 + lr;
      bv[nf] = b1[col[nf]];
    }
    float s[4] = {0.f, 0.f, 0.f, 0.f}, ss[4] = {0.f, 0.f, 0.f, 0.f};
    ushort_t* Elds = (ushort_t*)&Af[0][0];
#pragma unroll
    for (int h = 0; h < 2; ++h) {
      if (wr == h) {
#pragma unroll
        for (int mf = 0; mf < 4; ++mf) {
          int rl = mf * 16 + (lk << 2);
#pragma unroll
          for (int r = 0; r < 4; ++r) {
#pragma unroll
            for (int nf = 0; nf < 4; ++nf) {
              float hv = acc[mf][nf][r] + bv[nf];
              Elds[(rl + r) * 136 + col[nf]] = f2bf(hv);
              s[nf] += hv; ss[nf] += hv * hv;
            }
          }
        }
      }
      __syncthreads();
#pragma unroll
      for (int i = 0; i < 4; ++i) {
        int idx = tid + 256 * i;
        int row = idx >> 4, seg = idx & 15;
        uint4 v = *(const uint4*)(Elds + row * 136 + seg * 8);
        *(uint4*)(H1 + (row0 + h * 64 + row) * 128 + seg * 8) = v;
      }
      __syncthreads();
    }
#pragma unroll
    for (int nf = 0; nf < 4; ++nf) {
      atomicAdd(&lsum[col[nf]], s[nf]);
      atomicAdd(&lssq[col[nf]], ss[nf]);
    }
    __syncthreads();
    if (tid < 128) {
      atomicAdd(&csT[tid], lsum[tid]);
      atomicAdd(&cqT[tid], lssq[tid]);
    }
    __syncthreads();
  }
}

// ---------------------------------------------------------------------------
// BN params for encoder
// ---------------------------------------------------------------------------
__global__ void k_bn1(const float* __restrict__ colsum,
                      const float* __restrict__ colsumsq,
                      const float* __restrict__ g, const float* __restrict__ be,
                      float* __restrict__ scale, float* __restrict__ shift)
{
  int j = threadIdx.x;
  float mu = colsum[j] * (1.f / NROWS);
  float var = colsumsq[j] * (1.f / NROWS) - mu * mu;
  float sc = g[j] * rsqrtf(var + 1e-5f);
  scale[j] = sc;
  shift[j] = be[j] - mu * sc;
}

// ---------------------------------------------------------------------------
// K3: identical structure to round 7, wrapped in REPS_E loop.
// ---------------------------------------------------------------------------
__global__ __launch_bounds__(256, 4) void k_encode(
    const ushort_t* __restrict__ H1, const float* __restrict__ scale1,
    const float* __restrict__ shift1, const ushort_t* __restrict__ W2t,
    const float* __restrict__ b2, const ushort_t* __restrict__ CBb,
    const float* __restrict__ cn, int* __restrict__ topics,
    int* __restrict__ counts, float* __restrict__ Zloss,
    int* __restrict__ dumCounts, float* __restrict__ dumZ)
{
  __shared__ ushort_t Hb[64 * 128];
  __shared__ float Zt[64 * 33];
  __shared__ int hist[512];
  __shared__ float zsh;

  const int tid = threadIdx.x;
  const int lane = tid & 63;
  const int w = tid >> 6;
  const int lr = lane & 15;
  const int lk = lane >> 4;
  const int row0 = blockIdx.x * 64;

  for (int rep = 0; rep < REPS_E; ++rep) {
    int* cntT = (rep == 0) ? counts : dumCounts;
    float* zlT = (rep == 0) ? Zloss : dumZ;

    hist[tid] = 0; hist[tid + 256] = 0;
    if (tid == 0) zsh = 0.f;

    // ---- stage Hb ----
    {
      const int c8 = (tid & 15) * 8;
      const int rb = tid >> 4;
      float sc[8], sh[8];
      {
        float4 a = *(const float4*)(scale1 + c8);
        float4 b = *(const float4*)(scale1 + c8 + 4);
        sc[0]=a.x; sc[1]=a.y; sc[2]=a.z; sc[3]=a.w; sc[4]=b.x; sc[5]=b.y; sc[6]=b.z; sc[7]=b.w;
        float4 e = *(const float4*)(shift1 + c8);
        float4 f = *(const float4*)(shift1 + c8 + 4);
        sh[0]=e.x; sh[1]=e.y; sh[2]=e.z; sh[3]=e.w; sh[4]=f.x; sh[5]=f.y; sh[6]=f.z; sh[7]=f.w;
      }
#pragma unroll
      for (int j = 0; j < 4; ++j) {
        int r = rb + 16 * j;
        uint4 v = *(const uint4*)(H1 + (size_t)(row0 + r) * HDIM + c8);
        uint_t u[4] = {v.x, v.y, v.z, v.w};
        uint4 o;
        uint_t* op = (uint_t*)&o;
#pragma unroll
        for (int m = 0; m < 4; ++m) {
          float f0 = fmaxf(bflo(u[m]) * sc[2*m]   + sh[2*m],   0.f);
          float f1 = fmaxf(bfhi(u[m]) * sc[2*m+1] + sh[2*m+1], 0.f);
          op[m] = pk2(f0, f1);
        }
        *(uint4*)(Hb + r * 128 + ((((c8 >> 3) ^ (r & 7))) << 3)) = o;
      }
    }
    __syncthreads();

    // ---- phase A ----
    float zn4[4];
    {
      s16x8 af[4];
#pragma unroll
      for (int kt = 0; kt < 4; ++kt) {
        int m = w * 16 + lr;
        int b = kt * 4 + lk;
        af[kt] = *(const s16x8*)(Hb + m * 128 + ((b ^ (m & 7)) << 3));
      }
      f32x4 zacc[2];
      zacc[0] = (f32x4)(0.f); zacc[1] = (f32x4)(0.f);
#pragma unroll
      for (int ct = 0; ct < 2; ++ct)
#pragma unroll
        for (int kt = 0; kt < 4; ++kt) {
          s16x8 bf = *(const s16x8*)(W2t + (ct * 16 + lr) * 128 + kt * 32 + lk * 8);
          zacc[ct] = __builtin_amdgcn_mfma_f32_16x16x32_bf16(af[kt], bf, zacc[ct], 0, 0, 0);
        }
      float bias0 = b2[lr], bias1 = b2[16 + lr];
      float s4[4];
#pragma unroll
      for (int r = 0; r < 4; ++r) {
        float z0 = zacc[0][r] + bias0;
        float z1 = zacc[1][r] + bias1;
        int row = w * 16 + lk * 4 + r;
        Zt[row * 33 + lr] = z0;
        Zt[row * 33 + 16 + lr] = z1;
        s4[r] = z0 * z0 + z1 * z1;
      }
#pragma unroll
      for (int m = 1; m < 16; m <<= 1) {
#pragma unroll
        for (int r = 0; r < 4; ++r) s4[r] += __shfl_xor(s4[r], m, 64);
      }
#pragma unroll
      for (int r = 0; r < 4; ++r) zn4[r] = s4[r];
    }
    __syncthreads();

    // ---- phase B ----
    {
      s16x8 za;
      {
        const float* zp = Zt + (w * 16 + lr) * 33 + lk * 8;
        float4 q0 = *(const float4*)(zp);
        float4 q1 = *(const float4*)(zp + 4);
        union { s16x8 v; uint_t u[4]; } zu;
        zu.u[0] = pk2(q0.x, q0.y);
        zu.u[1] = pk2(q0.z, q0.w);
        zu.u[2] = pk2(q1.x, q1.y);
        zu.u[3] = pk2(q1.z, q1.w);
        za = zu.v;
      }
      float minv[4] = {3.4e38f, 3.4e38f, 3.4e38f, 3.4e38f};
      int mini[4] = {0, 0, 0, 0};
#pragma unroll 4
      for (int t = 0; t < 32; ++t) {
        const int c = t * 16 + lr;
        s16x8 cb = *(const s16x8*)(CBb + c * 32 + lk * 8);
        f32x4 dot = __builtin_amdgcn_mfma_f32_16x16x32_bf16(za, cb, (f32x4)(0.f), 0, 0, 0);
        float cnv = cn[c];
#pragma unroll
        for (int r = 0; r < 4; ++r) {
          float d = fmaf(-2.f, dot[r], cnv);
          if (d < minv[r]) { minv[r] = d; mini[r] = c; }
        }
      }
#pragma unroll
      for (int m = 1; m < 16; m <<= 1) {
#pragma unroll
        for (int r = 0; r < 4; ++r) {
          float ov = __shfl_xor(minv[r], m, 64);
          int   oi = __shfl_xor(mini[r], m, 64);
          if (ov < minv[r] || (ov == minv[r] && oi < mini[r])) { minv[r] = ov; mini[r] = oi; }
        }
      }
      if (lr == 0) {
        float part = 0.f;
#pragma unroll
        for (int r = 0; r < 4; ++r) {
          int row = row0 + w * 16 + lk * 4 + r;
          topics[row] = mini[r];
          atomicAdd(&hist[mini[r]], 1);
          part += minv[r] + zn4[r];
        }
        atomicAdd(&zsh, part);
      }
    }
    __syncthreads();
    {
      int h0 = hist[tid], h1 = hist[tid + 256];
      if (h0) atomicAdd(&cntT[tid], h0);
      if (h1) atomicAdd(&cntT[tid + 256], h1);
      if (tid == 0) atomicAdd(zlT, zsh);
    }
    __syncthreads();
  }
}

// Decoder BN params from topic histogram (exact batch stats)
__global__ void k_bn2(const int* __restrict__ counts, const float* __restrict__ T,
    const float* __restrict__ g, const float* __restrict__ be,
    float* __restrict__ scale2, float* __restrict__ shift2)
{
  __shared__ float cw[512];
  int j = threadIdx.x;  // 128
  for (int i = j; i < 512; i += 128) cw[i] = (float)counts[i];
  __syncthreads();
  float s = 0.f, ss = 0.f;
  for (int k = 0; k < KCODES; ++k) {
    float t = T[k * HDIM + j];
    float c = cw[k];
    s += c * t; ss += c * t * t;
  }
  float mu = s * (1.f / NROWS);
  float var = ss * (1.f / NROWS) - mu * mu;
  float sc = g[j] * rsqrtf(var + 1e-5f);
  scale2[j] = sc;
  shift2[j] = be[j] - mu * sc;
}

// U = relu(bn(T)) @ dec_W2 + dec_b2   [512 x 512]
__global__ __launch_bounds__(256) void k_U(const float* __restrict__ T,
    const float* __restrict__ scale2, const float* __restrict__ shift2,
    const float* __restrict__ dW2, const float* __restrict__ db2,
    float* __restrict__ U)
{
  __shared__ float Tb[128];
  const int tid = threadIdx.x;
  const int k = blockIdx.x >> 1;
  const int c = (blockIdx.x & 1) * 256 + tid;
  if (tid < 128) Tb[tid] = fmaxf(T[k * HDIM + tid] * scale2[tid] + shift2[tid], 0.f);
  __syncthreads();
  float acc = db2[c];
#pragma unroll 8
  for (int j = 0; j < HDIM; ++j) acc += Tb[j] * dW2[j * 512 + c];
  U[(size_t)k * 512 + c] = acc;
}

// Reconstruction wrapped in REPS_R loop.
__global__ __launch_bounds__(256, 4) void k_recon(
    const float* __restrict__ X, const float* __restrict__ U,
    const int* __restrict__ topics, float* __restrict__ Rsum,
    float* __restrict__ dumR)
{
  __shared__ float bsum;
  const int tid = threadIdx.x;
  const int lane = tid & 63;
  const int wave = blockIdx.x * 4 + (tid >> 6);

  for (int rep = 0; rep < REPS_R; ++rep) {
    float* rT = (rep == 0) ? Rsum : dumR;
    if (tid == 0) bsum = 0.f;
    __syncthreads();
    float acc = 0.f;
    for (int r = wave; r < NROWS; r += 4096) {
      const int t = topics[r];
      const float4* xr = (const float4*)(X + (size_t)r * DIN);
      const float4* ur = (const float4*)(U + (size_t)t * 512);
      float4 x0 = xr[lane],      u0 = ur[lane];
      float4 x1 = xr[lane + 64], u1 = ur[lane + 64];
      float d;
      d = x0.x - u0.x; acc += d * d;
      d = x0.y - u0.y; acc += d * d;
      d = x0.z - u0.z; acc += d * d;
      d = x0.w - u0.w; acc += d * d;
      d = x1.x - u1.x; acc += d * d;
      d = x1.y - u1.y; acc += d * d;
      d = x1.z - u1.z; acc += d * d;
      d = x1.w - u1.w; acc += d * d;
    }
#pragma unroll
    for (int off = 32; off > 0; off >>= 1) acc += __shfl_down(acc, off, 64);
    if (lane == 0) atomicAdd(&bsum, acc);
    __syncthreads();
    if (tid == 0) atomicAdd(rT, bsum);
  }
}

__global__ void k_final(const float* __restrict__ Zloss,
                        const float* __restrict__ Rsum, float* __restrict__ out)
{
  out[0] = 2.f * Zloss[0] + sqrtf(Rsum[0]);
}

// ---------------------------------------------------------------------------
// Workspace layout (bytes): as round 7, plus diagnostic dummy scratch at 40 MB
// (never read; never zeroed; accumulates garbage — outputs don't depend on it).
// ---------------------------------------------------------------------------
extern "C" void kernel_launch(void* const* d_in, const int* in_sizes, int n_in,
                              void* d_out, int out_size, void* d_ws, size_t ws_size,
                              hipStream_t stream) {
  const float* X    = (const float*)d_in[0];
  const float* eW1  = (const float*)d_in[1];
  const float* eb1  = (const float*)d_in[2];
  const float* eg1  = (const float*)d_in[3];
  const float* ebe1 = (const float*)d_in[4];
  const float* eW2  = (const float*)d_in[5];
  const float* eb2  = (const float*)d_in[6];
  const float* CB   = (const float*)d_in[7];
  const float* dW1  = (const float*)d_in[8];
  const float* db1  = (const float*)d_in[9];
  const float* dg1  = (const float*)d_in[10];
  const float* dbe1 = (const float*)d_in[11];
  const float* dW2  = (const float*)d_in[12];
  const float* db2  = (const float*)d_in[13];
  float* out = (float*)d_out;

  char* wsb = (char*)d_ws;
  ushort_t* H1    = (ushort_t*)wsb;
  int* topics     = (int*)(wsb + 33554432);
  float* colsum   = (float*)(wsb + 34078720);
  float* colsumsq = colsum + 128;
  int* counts     = (int*)(wsb + 34078720 + 1024);
  float* Zloss    = (float*)(wsb + 34078720 + 3072);
  float* Rsum     = Zloss + 1;
  float* scale1   = (float*)(wsb + 34082816);
  float* shift1   = scale1 + 128;
  float* cn       = (float*)(wsb + 34083840);
  float* T        = (float*)(wsb + 34085888);
  float* scale2   = (float*)(wsb + 34348032);
  float* shift2   = scale2 + 128;
  float* U        = (float*)(wsb + 34349056);
  ushort_t* W1t   = (ushort_t*)(wsb + 34349056);  // aliases U (disjoint lifetime)
  ushort_t* W2t   = (ushort_t*)(wsb + 35397632);
  ushort_t* CBb   = (ushort_t*)(wsb + 35405824);
  // diagnostic dummies @ 40 MB
  float* dumA     = (float*)(wsb + 41943040);          // 128 f32
  float* dumB     = dumA + 128;                        // 128 f32
  int*   dumCnt   = (int*)(wsb + 41943040 + 1024);     // 512 i32
  float* dumZ     = (float*)(wsb + 41943040 + 3072);   // 1 f32
  float* dumR     = dumZ + 1;                          // 1 f32

  k_prep<<<256, 256, 0, stream>>>(eW1, eW2, CB, dW1, db1, W1t, W2t, CBb, cn, T,
                                  colsum);
  k_gemm1<<<NROWS / 128, 256, 0, stream>>>(X, W1t, eb1, H1, colsum, colsumsq,
                                           dumA, dumB);
  k_bn1<<<1, 128, 0, stream>>>(colsum, colsumsq, eg1, ebe1, scale1, shift1);
  k_encode<<<NROWS / 64, 256, 0, stream>>>(H1, scale1, shift1, W2t, eb2, CBb, cn,
                                           topics, counts, Zloss, dumCnt, dumZ);
  k_bn2<<<1, 128, 0, stream>>>(counts, T, dg1, dbe1, scale2, shift2);
  k_U<<<KCODES * 2, 256, 0, stream>>>(T, scale2, shift2, dW2, db2, U);
  k_recon<<<1024, 256, 0, stream>>>(X, U, topics, Rsum, dumR);
  k_final<<<1, 1, 0, stream>>>(Zloss, Rsum, out);
}

// Round 9
// 340.468 us; speedup vs baseline: 4.2730x; 4.2730x over previous
//
#include <hip/hip_runtime.h>
#include <hip/hip_bf16.h>

// Problem constants (from setup_inputs)
#define NROWS 131072
#define DIN   512
#define HDIM  128
#define EDIM  32
#define KCODES 512

typedef unsigned short ushort_t;
typedef unsigned int   uint_t;
typedef float f32x4 __attribute__((ext_vector_type(4)));
typedef short s16x8 __attribute__((ext_vector_type(8)));

// ---------- bf16 helpers ----------
__device__ __forceinline__ float bflo(uint_t u) {
  union { uint_t u; float f; } x; x.u = u << 16; return x.f;
}
__device__ __forceinline__ float bfhi(uint_t u) {
  union { uint_t u; float f; } x; x.u = u & 0xffff0000u; return x.f;
}
__device__ __forceinline__ ushort_t f2bf(float f) {   // RNE (off hot path)
  union { float f; uint_t u; } x; x.f = f;
  uint_t u = x.u;
  return (ushort_t)((u + 0x7fffu + ((u >> 16) & 1u)) >> 16);
}
// pack-truncate 2 fp32 -> (bf16(hi)<<16)|bf16(lo) in ONE v_perm_b32.
__device__ __forceinline__ uint_t pk2(float lo, float hi) {
  return __builtin_amdgcn_perm(__float_as_uint(hi), __float_as_uint(lo), 0x07060302u);
}

// ---------------------------------------------------------------------------
// k_prep: W1t bf16[n][k], W2t bf16[e][k], CBb bf16[c][e], cn, decoder table
// T = CB@dec_W1 + db1, zero accumulators. grid 256 x 256.
// ---------------------------------------------------------------------------
__global__ __launch_bounds__(256) void k_prep(
    const float* __restrict__ W1, const float* __restrict__ W2,
    const float* __restrict__ CB, const float* __restrict__ dW1,
    const float* __restrict__ db1,
    ushort_t* __restrict__ W1t, ushort_t* __restrict__ W2t,
    ushort_t* __restrict__ CBb, float* __restrict__ cn,
    float* __restrict__ T, float* __restrict__ accz)
{
  int gid = blockIdx.x * 256 + threadIdx.x;   // 0..65535
  {
    W1t[gid] = f2bf(W1[(gid & 511) * 128 + (gid >> 9)]);  // [n][k] <- [k][n]
  }
  {
    int k = gid >> 7, j = gid & 127;          // T[k][j], 512x128
    float acc = db1[j];
#pragma unroll
    for (int e = 0; e < EDIM; ++e) acc += CB[k * EDIM + e] * dW1[e * HDIM + j];
    T[gid] = acc;
  }
  if (gid < 16384) CBb[gid] = f2bf(CB[gid]);
  if (gid < 4096) {
    int e = gid >> 7, k = gid & 127;
    W2t[gid] = f2bf(W2[k * 32 + e]);
  }
  if (gid < 512) {
    float s = 0.f;
#pragma unroll
    for (int e = 0; e < EDIM; ++e) { float c = CB[gid * EDIM + e]; s += c * c; }
    cn[gid] = s;
  }
  if (gid < 1024) accz[gid] = 0.f;
}

// ---------------------------------------------------------------------------
// K1 (REWRITE): barrier-free streaming MFMA GEMM.
// Each wave owns 16 rows of X; per K-slice (32): 1 A-frag direct from global
// (fp32 -> pk2 bf16), 8 B-frags from L2-resident W1t, 8 MFMAs. NO __syncthreads
// in the main loop -> no vmcnt drain; latency hidden by 24-32 waves/CU.
// Epilogue: per-wave LDS transpose -> coalesced uint4 H1; block BN stats.
// grid 2048 x 256 (4 waves x 16 rows = 64 rows/block).
// ---------------------------------------------------------------------------
__global__ __launch_bounds__(256, 4) void k_gemm1(
    const float* __restrict__ X, const ushort_t* __restrict__ W1t,
    const float* __restrict__ b1, ushort_t* __restrict__ H1,
    float* __restrict__ colsum, float* __restrict__ colsumsq)
{
  __shared__ ushort_t Elds[4][16 * 136];   // per-wave epilogue transpose (17.4 KB)
  __shared__ float lsum[128], lssq[128];
  const int tid = threadIdx.x;
  const int lane = tid & 63;
  const int wid = tid >> 6;
  const int lr = lane & 15;     // A row / B col within 16
  const int lk = lane >> 4;     // k quad (8 elems)
  const size_t rw = (size_t)blockIdx.x * 64 + wid * 16;   // wave's 16 rows

  if (tid < 128) { lsum[tid] = 0.f; lssq[tid] = 0.f; }
  __syncthreads();   // lsum/lssq ready before any wave's epilogue (only barrier pre-loop)

  const float* xrow = X + (rw + lr) * 512 + lk * 8;

  f32x4 acc[8];
#pragma unroll
  for (int cf = 0; cf < 8; ++cf) acc[cf] = (f32x4)(0.f);

#pragma unroll 4
  for (int ks = 0; ks < 16; ++ks) {
    // A fragment: 8 consecutive fp32 from this lane's row -> bf16
    f32x4 a0 = *(const f32x4*)(xrow + ks * 32);
    f32x4 a1 = *(const f32x4*)(xrow + ks * 32 + 4);
    union { s16x8 v; uint_t u[4]; } t;
    t.u[0] = pk2(a0[0], a0[1]);
    t.u[1] = pk2(a0[2], a0[3]);
    t.u[2] = pk2(a1[0], a1[1]);
    t.u[3] = pk2(a1[2], a1[3]);
    s16x8 af = t.v;
    // B fragments (L2-resident W1t) + MFMA
#pragma unroll
    for (int cf = 0; cf < 8; ++cf) {
      s16x8 bf = *(const s16x8*)(W1t + (cf * 16 + lr) * 512 + ks * 32 + lk * 8);
      acc[cf] = __builtin_amdgcn_mfma_f32_16x16x32_bf16(af, bf, acc[cf], 0, 0, 0);
    }
  }

  // ---- epilogue ----
  // C/D layout: col = lane&15 (=lr), row = (lane>>4)*4 + r (=lk*4+r)  [m89]
  float s[8], ss[8];
#pragma unroll
  for (int cf = 0; cf < 8; ++cf) { s[cf] = 0.f; ss[cf] = 0.f; }
#pragma unroll
  for (int cf = 0; cf < 8; ++cf) {
    float bv = b1[cf * 16 + lr];
#pragma unroll
    for (int r = 0; r < 4; ++r) {
      float hv = acc[cf][r] + bv;
      s[cf] += hv; ss[cf] += hv * hv;
      Elds[wid][(lk * 4 + r) * 136 + cf * 16 + lr] = f2bf(hv);
    }
  }
  asm volatile("s_waitcnt lgkmcnt(0)" ::: "memory");  // wave-local LDS ordering
  // coalesced H1 stores: 16 rows x 128 bf16 per wave
#pragma unroll
  for (int i = 0; i < 4; ++i) {
    int idx = lane + 64 * i;         // 0..255
    int row = idx >> 4, seg = idx & 15;
    uint4 v = *(const uint4*)(&Elds[wid][row * 136 + seg * 8]);
    *(uint4*)(H1 + (rw + row) * 128 + seg * 8) = v;
  }
  // BN stats: LDS atomics then one global atomic per col per block
#pragma unroll
  for (int cf = 0; cf < 8; ++cf) {
    atomicAdd(&lsum[cf * 16 + lr], s[cf]);
    atomicAdd(&lssq[cf * 16 + lr], ss[cf]);
  }
  __syncthreads();
  if (tid < 128) {
    atomicAdd(&colsum[tid], lsum[tid]);
    atomicAdd(&colsumsq[tid], lssq[tid]);
  }
}

// ---------------------------------------------------------------------------
// BN params for encoder
// ---------------------------------------------------------------------------
__global__ void k_bn1(const float* __restrict__ colsum,
                      const float* __restrict__ colsumsq,
                      const float* __restrict__ g, const float* __restrict__ be,
                      float* __restrict__ scale, float* __restrict__ shift)
{
  int j = threadIdx.x;
  float mu = colsum[j] * (1.f / NROWS);
  float var = colsumsq[j] * (1.f / NROWS) - mu * mu;
  float sc = g[j] * rsqrtf(var + 1e-5f);
  scale[j] = sc;
  shift[j] = be[j] - mu * sc;
}

// ---------------------------------------------------------------------------
// K3: BN+ReLU -> Z = Hb@W2 (MFMA) -> dists Z@CBb^T (MFMA K=32) + argmin.
// 64 rows/block, 4 waves x 16 rows.  (validated; unchanged)
// ---------------------------------------------------------------------------
__global__ __launch_bounds__(256, 4) void k_encode(
    const ushort_t* __restrict__ H1, const float* __restrict__ scale1,
    const float* __restrict__ shift1, const ushort_t* __restrict__ W2t,
    const float* __restrict__ b2, const ushort_t* __restrict__ CBb,
    const float* __restrict__ cn, int* __restrict__ topics,
    int* __restrict__ counts, float* __restrict__ Zloss)
{
  __shared__ ushort_t Hb[64 * 128];
  __shared__ float Zt[64 * 33];
  __shared__ int hist[512];
  __shared__ float zsh;

  const int tid = threadIdx.x;
  const int lane = tid & 63;
  const int w = tid >> 6;
  const int lr = lane & 15;
  const int lk = lane >> 4;
  const int row0 = blockIdx.x * 64;

  hist[tid] = 0; hist[tid + 256] = 0;
  if (tid == 0) zsh = 0.f;

  // ---- stage Hb: BN+ReLU applied, bf16 (pk2-truncated), swizzled ----
  {
    const int c8 = (tid & 15) * 8;
    const int rb = tid >> 4;
    float sc[8], sh[8];
    {
      float4 a = *(const float4*)(scale1 + c8);
      float4 b = *(const float4*)(scale1 + c8 + 4);
      sc[0]=a.x; sc[1]=a.y; sc[2]=a.z; sc[3]=a.w; sc[4]=b.x; sc[5]=b.y; sc[6]=b.z; sc[7]=b.w;
      float4 e = *(const float4*)(shift1 + c8);
      float4 f = *(const float4*)(shift1 + c8 + 4);
      sh[0]=e.x; sh[1]=e.y; sh[2]=e.z; sh[3]=e.w; sh[4]=f.x; sh[5]=f.y; sh[6]=f.z; sh[7]=f.w;
    }
#pragma unroll
    for (int j = 0; j < 4; ++j) {
      int r = rb + 16 * j;
      uint4 v = *(const uint4*)(H1 + (size_t)(row0 + r) * HDIM + c8);
      uint_t u[4] = {v.x, v.y, v.z, v.w};
      uint4 o;
      uint_t* op = (uint_t*)&o;
#pragma unroll
      for (int m = 0; m < 4; ++m) {
        float f0 = fmaxf(bflo(u[m]) * sc[2*m]   + sh[2*m],   0.f);
        float f1 = fmaxf(bfhi(u[m]) * sc[2*m+1] + sh[2*m+1], 0.f);
        op[m] = pk2(f0, f1);
      }
      *(uint4*)(Hb + r * 128 + ((((c8 >> 3) ^ (r & 7))) << 3)) = o;
    }
  }
  __syncthreads();

  // ---- phase A: Z = Hb @ W2t + b2 (MFMA, K=128) ----
  float zn4[4];
  {
    s16x8 af[4];
#pragma unroll
    for (int kt = 0; kt < 4; ++kt) {
      int m = w * 16 + lr;
      int b = kt * 4 + lk;
      af[kt] = *(const s16x8*)(Hb + m * 128 + ((b ^ (m & 7)) << 3));
    }
    f32x4 zacc[2];
    zacc[0] = (f32x4)(0.f); zacc[1] = (f32x4)(0.f);
#pragma unroll
    for (int ct = 0; ct < 2; ++ct)
#pragma unroll
      for (int kt = 0; kt < 4; ++kt) {
        s16x8 bf = *(const s16x8*)(W2t + (ct * 16 + lr) * 128 + kt * 32 + lk * 8);
        zacc[ct] = __builtin_amdgcn_mfma_f32_16x16x32_bf16(af[kt], bf, zacc[ct], 0, 0, 0);
      }
    float bias0 = b2[lr], bias1 = b2[16 + lr];
    float s4[4];
#pragma unroll
    for (int r = 0; r < 4; ++r) {
      float z0 = zacc[0][r] + bias0;
      float z1 = zacc[1][r] + bias1;
      int row = w * 16 + lk * 4 + r;
      Zt[row * 33 + lr] = z0;
      Zt[row * 33 + 16 + lr] = z1;
      s4[r] = z0 * z0 + z1 * z1;
    }
#pragma unroll
    for (int m = 1; m < 16; m <<= 1) {
#pragma unroll
      for (int r = 0; r < 4; ++r) s4[r] += __shfl_xor(s4[r], m, 64);
    }
#pragma unroll
    for (int r = 0; r < 4; ++r) zn4[r] = s4[r];
  }
  __syncthreads();

  // ---- phase B: distances via MFMA (K=32), running argmin ----
  {
    s16x8 za;
    {
      const float* zp = Zt + (w * 16 + lr) * 33 + lk * 8;
      float4 q0 = *(const float4*)(zp);
      float4 q1 = *(const float4*)(zp + 4);
      union { s16x8 v; uint_t u[4]; } zu;
      zu.u[0] = pk2(q0.x, q0.y);
      zu.u[1] = pk2(q0.z, q0.w);
      zu.u[2] = pk2(q1.x, q1.y);
      zu.u[3] = pk2(q1.z, q1.w);
      za = zu.v;
    }
    float minv[4] = {3.4e38f, 3.4e38f, 3.4e38f, 3.4e38f};
    int mini[4] = {0, 0, 0, 0};
#pragma unroll 4
    for (int t = 0; t < 32; ++t) {
      const int c = t * 16 + lr;
      s16x8 cb = *(const s16x8*)(CBb + c * 32 + lk * 8);
      f32x4 dot = __builtin_amdgcn_mfma_f32_16x16x32_bf16(za, cb, (f32x4)(0.f), 0, 0, 0);
      float cnv = cn[c];
#pragma unroll
      for (int r = 0; r < 4; ++r) {
        float d = fmaf(-2.f, dot[r], cnv);
        if (d < minv[r]) { minv[r] = d; mini[r] = c; }
      }
    }
#pragma unroll
    for (int m = 1; m < 16; m <<= 1) {
#pragma unroll
      for (int r = 0; r < 4; ++r) {
        float ov = __shfl_xor(minv[r], m, 64);
        int   oi = __shfl_xor(mini[r], m, 64);
        if (ov < minv[r] || (ov == minv[r] && oi < mini[r])) { minv[r] = ov; mini[r] = oi; }
      }
    }
    if (lr == 0) {
      float part = 0.f;
#pragma unroll
      for (int r = 0; r < 4; ++r) {
        int row = row0 + w * 16 + lk * 4 + r;
        topics[row] = mini[r];
        atomicAdd(&hist[mini[r]], 1);
        part += minv[r] + zn4[r];
      }
      atomicAdd(&zsh, part);
    }
  }
  __syncthreads();
  {
    int h0 = hist[tid], h1 = hist[tid + 256];
    if (h0) atomicAdd(&counts[tid], h0);
    if (h1) atomicAdd(&counts[tid + 256], h1);
    if (tid == 0) atomicAdd(Zloss, zsh);
  }
}

// Decoder BN params from topic histogram (exact batch stats)
__global__ void k_bn2(const int* __restrict__ counts, const float* __restrict__ T,
    const float* __restrict__ g, const float* __restrict__ be,
    float* __restrict__ scale2, float* __restrict__ shift2)
{
  __shared__ float cw[512];
  int j = threadIdx.x;  // 128
  for (int i = j; i < 512; i += 128) cw[i] = (float)counts[i];
  __syncthreads();
  float s = 0.f, ss = 0.f;
  for (int k = 0; k < KCODES; ++k) {
    float t = T[k * HDIM + j];
    float c = cw[k];
    s += c * t; ss += c * t * t;
  }
  float mu = s * (1.f / NROWS);
  float var = ss * (1.f / NROWS) - mu * mu;
  float sc = g[j] * rsqrtf(var + 1e-5f);
  scale2[j] = sc;
  shift2[j] = be[j] - mu * sc;
}

// U = relu(bn(T)) @ dec_W2 + dec_b2   [512 x 512]
__global__ __launch_bounds__(256) void k_U(const float* __restrict__ T,
    const float* __restrict__ scale2, const float* __restrict__ shift2,
    const float* __restrict__ dW2, const float* __restrict__ db2,
    float* __restrict__ U)
{
  __shared__ float Tb[128];
  const int tid = threadIdx.x;
  const int k = blockIdx.x >> 1;
  const int c = (blockIdx.x & 1) * 256 + tid;
  if (tid < 128) Tb[tid] = fmaxf(T[k * HDIM + tid] * scale2[tid] + shift2[tid], 0.f);
  __syncthreads();
  float acc = db2[c];
#pragma unroll 8
  for (int j = 0; j < HDIM; ++j) acc += Tb[j] * dW2[j * 512 + c];
  U[(size_t)k * 512 + c] = acc;
}

// Reconstruction: R += sum_n ||U[topic[n]] - X[n]||^2
__global__ __launch_bounds__(256, 4) void k_recon(
    const float* __restrict__ X, const float* __restrict__ U,
    const int* __restrict__ topics, float* __restrict__ Rsum)
{
  __shared__ float bsum;
  const int tid = threadIdx.x;
  if (tid == 0) bsum = 0.f;
  __syncthreads();
  const int lane = tid & 63;
  const int wave = blockIdx.x * 4 + (tid >> 6);
  float acc = 0.f;
  for (int r = wave; r < NROWS; r += 4096) {
    const int t = topics[r];
    const float4* xr = (const float4*)(X + (size_t)r * DIN);
    const float4* ur = (const float4*)(U + (size_t)t * 512);
    float4 x0 = xr[lane],      u0 = ur[lane];
    float4 x1 = xr[lane + 64], u1 = ur[lane + 64];
    float d;
    d = x0.x - u0.x; acc += d * d;
    d = x0.y - u0.y; acc += d * d;
    d = x0.z - u0.z; acc += d * d;
    d = x0.w - u0.w; acc += d * d;
    d = x1.x - u1.x; acc += d * d;
    d = x1.y - u1.y; acc += d * d;
    d = x1.z - u1.z; acc += d * d;
    d = x1.w - u1.w; acc += d * d;
  }
#pragma unroll
  for (int off = 32; off > 0; off >>= 1) acc += __shfl_down(acc, off, 64);
  if (lane == 0) atomicAdd(&bsum, acc);
  __syncthreads();
  if (tid == 0) atomicAdd(Rsum, bsum);
}

__global__ void k_final(const float* __restrict__ Zloss,
                        const float* __restrict__ Rsum, float* __restrict__ out)
{
  out[0] = 2.f * Zloss[0] + sqrtf(Rsum[0]);
}

// ---------------------------------------------------------------------------
// Workspace layout (bytes):
//   0         H1 bf16            [N*128]      33,554,432
//   33554432  topics int32       [N]             524,288
//   34078720  accumulators (zeroed by k_prep, 4 KB)
//   34082816  scale1[128]+shift1[128]
//   34083840  cn[512] f32
//   34085888  T[512*128] f32                   262,144
//   34348032  scale2[128]+shift2[128]
//   34349056  U[512*512] f32                 1,048,576  (W1t bf16 aliases; disjoint lifetime)
//   35397632  W2t bf16 [32][128]
//   35405824  CBb bf16 [512][32]
// ---------------------------------------------------------------------------
extern "C" void kernel_launch(void* const* d_in, const int* in_sizes, int n_in,
                              void* d_out, int out_size, void* d_ws, size_t ws_size,
                              hipStream_t stream) {
  const float* X    = (const float*)d_in[0];
  const float* eW1  = (const float*)d_in[1];
  const float* eb1  = (const float*)d_in[2];
  const float* eg1  = (const float*)d_in[3];
  const float* ebe1 = (const float*)d_in[4];
  const float* eW2  = (const float*)d_in[5];
  const float* eb2  = (const float*)d_in[6];
  const float* CB   = (const float*)d_in[7];
  const float* dW1  = (const float*)d_in[8];
  const float* db1  = (const float*)d_in[9];
  const float* dg1  = (const float*)d_in[10];
  const float* dbe1 = (const float*)d_in[11];
  const float* dW2  = (const float*)d_in[12];
  const float* db2  = (const float*)d_in[13];
  float* out = (float*)d_out;

  char* wsb = (char*)d_ws;
  ushort_t* H1    = (ushort_t*)wsb;
  int* topics     = (int*)(wsb + 33554432);
  float* colsum   = (float*)(wsb + 34078720);
  float* colsumsq = colsum + 128;
  int* counts     = (int*)(wsb + 34078720 + 1024);
  float* Zloss    = (float*)(wsb + 34078720 + 3072);
  float* Rsum     = Zloss + 1;
  float* scale1   = (float*)(wsb + 34082816);
  float* shift1   = scale1 + 128;
  float* cn       = (float*)(wsb + 34083840);
  float* T        = (float*)(wsb + 34085888);
  float* scale2   = (float*)(wsb + 34348032);
  float* shift2   = scale2 + 128;
  float* U        = (float*)(wsb + 34349056);
  ushort_t* W1t   = (ushort_t*)(wsb + 34349056);  // aliases U (disjoint lifetime)
  ushort_t* W2t   = (ushort_t*)(wsb + 35397632);
  ushort_t* CBb   = (ushort_t*)(wsb + 35405824);

  k_prep<<<256, 256, 0, stream>>>(eW1, eW2, CB, dW1, db1, W1t, W2t, CBb, cn, T,
                                  colsum);
  k_gemm1<<<NROWS / 64, 256, 0, stream>>>(X, W1t, eb1, H1, colsum, colsumsq);
  k_bn1<<<1, 128, 0, stream>>>(colsum, colsumsq, eg1, ebe1, scale1, shift1);
  k_encode<<<NROWS / 64, 256, 0, stream>>>(H1, scale1, shift1, W2t, eb2, CBb, cn,
                                           topics, counts, Zloss);
  k_bn2<<<1, 128, 0, stream>>>(counts, T, dg1, dbe1, scale2, shift2);
  k_U<<<KCODES * 2, 256, 0, stream>>>(T, scale2, shift2, dW2, db2, U);
  k_recon<<<1024, 256, 0, stream>>>(X, U, topics, Rsum);
  k_final<<<1, 1, 0, stream>>>(Zloss, Rsum, out);
}

// Round 10
// 223.085 us; speedup vs baseline: 6.5213x; 1.5262x over previous
//
#include <hip/hip_runtime.h>
#include <hip/hip_bf16.h>

// Problem constants (from setup_inputs)
#define NROWS 131072
#define DIN   512
#define HDIM  128
#define EDIM  32
#define KCODES 512

typedef unsigned short ushort_t;
typedef unsigned int   uint_t;
typedef float f32x4 __attribute__((ext_vector_type(4)));
typedef short s16x8 __attribute__((ext_vector_type(8)));

// ---------- bf16 helpers ----------
__device__ __forceinline__ float bflo(uint_t u) {
  union { uint_t u; float f; } x; x.u = u << 16; return x.f;
}
__device__ __forceinline__ float bfhi(uint_t u) {
  union { uint_t u; float f; } x; x.u = u & 0xffff0000u; return x.f;
}
__device__ __forceinline__ ushort_t f2bf(float f) {   // RNE (off hot path)
  union { float f; uint_t u; } x; x.f = f;
  uint_t u = x.u;
  return (ushort_t)((u + 0x7fffu + ((u >> 16) & 1u)) >> 16);
}
// pack-truncate 2 fp32 -> (bf16(hi)<<16)|bf16(lo) in ONE v_perm_b32.
__device__ __forceinline__ uint_t pk2(float lo, float hi) {
  return __builtin_amdgcn_perm(__float_as_uint(hi), __float_as_uint(lo), 0x07060302u);
}

// ---------------------------------------------------------------------------
// k_prep: W1f = FRAGMENT-MAJOR bf16 W1 (the key change):
//   tile t = c16*16 + kk  (c16 = col-group of 16, kk = k-chunk of 32)
//   W1f[t*512 + lane*8 + j] = W1[(kk*32 + (lane>>4)*8 + j)*128 + c16*16 + (lane&15)]
// -> a wave's B-fragment load is ONE contiguous 1KB segment (was 16 segments).
// Also: W2t, CBb, cn, decoder table T, zero accumulators. grid 256 x 256.
// ---------------------------------------------------------------------------
__global__ __launch_bounds__(256) void k_prep(
    const float* __restrict__ W1, const float* __restrict__ W2,
    const float* __restrict__ CB, const float* __restrict__ dW1,
    const float* __restrict__ db1,
    ushort_t* __restrict__ W1f, ushort_t* __restrict__ W2t,
    ushort_t* __restrict__ CBb, float* __restrict__ cn,
    float* __restrict__ T, float* __restrict__ accz)
{
  int gid = blockIdx.x * 256 + threadIdx.x;   // 0..65535
  {
    int t = gid >> 9, lane = (gid >> 3) & 63, j = gid & 7;
    int c16 = t >> 4, kk = t & 15, lr = lane & 15, lk = lane >> 4;
    W1f[gid] = f2bf(W1[(kk * 32 + lk * 8 + j) * 128 + c16 * 16 + lr]);
  }
  {
    int k = gid >> 7, j = gid & 127;          // T[k][j], 512x128
    float acc = db1[j];
#pragma unroll
    for (int e = 0; e < EDIM; ++e) acc += CB[k * EDIM + e] * dW1[e * HDIM + j];
    T[gid] = acc;
  }
  if (gid < 16384) CBb[gid] = f2bf(CB[gid]);
  if (gid < 4096) {
    int e = gid >> 7, k = gid & 127;
    W2t[gid] = f2bf(W2[k * 32 + e]);
  }
  if (gid < 512) {
    float s = 0.f;
#pragma unroll
    for (int e = 0; e < EDIM; ++e) { float c = CB[gid * EDIM + e]; s += c * c; }
    cn[gid] = s;
  }
  if (gid < 1024) accz[gid] = 0.f;
}

// ---------------------------------------------------------------------------
// K1: round-6 skeleton (reg-staged A, double-buffered LDS, 1 barrier/K-step,
// coalesced epilogue) with B loads from FRAGMENT-MAJOR W1f (1-segment reads).
// ---------------------------------------------------------------------------
__global__ __launch_bounds__(256, 2) void k_gemm1(
    const float* __restrict__ X, const ushort_t* __restrict__ W1f,
    const float* __restrict__ b1, ushort_t* __restrict__ H1,
    float* __restrict__ colsum, float* __restrict__ colsumsq)
{
  __shared__ ushort_t Alds[2][128 * 64];   // 32 KB, swizzled; epilogue reuses
  __shared__ float lsum[128], lssq[128];
  const int tid = threadIdx.x;
  const int lane = tid & 63;
  const int wid = tid >> 6;
  const int wr = wid >> 1, wc = wid & 1;
  const size_t row0 = (size_t)blockIdx.x * 128;
  if (tid < 128) { lsum[tid] = 0.f; lssq[tid] = 0.f; }

  f32x4 acc[4][4];
#pragma unroll
  for (int i = 0; i < 4; ++i)
#pragma unroll
    for (int j = 0; j < 4; ++j) acc[i][j] = (f32x4)(0.f);

  const int k4 = tid & 15;       // A stage: k quad (fixed)
  const int rbase = tid >> 4;    // A stage: row base (+16j)
  const int wofs = rbase * 64 + (((k4 >> 1) ^ (rbase & 7)) << 3) + (k4 & 1) * 4;

  // B fragment bases in fragment-major W1f: tile (wc*4+nf)*16 + (it*2+km)
  int bofs[4];
#pragma unroll
  for (int nf = 0; nf < 4; ++nf)
    bofs[nf] = ((wc * 4 + nf) << 13) + lane * 8;   // (wc*4+nf)*16*512 + lane*8

  int aofs[4][2];
#pragma unroll
  for (int mf = 0; mf < 4; ++mf) {
    int a_r = wr * 64 + mf * 16 + (lane & 15);
#pragma unroll
    for (int km = 0; km < 2; ++km) {
      int b = km * 4 + (lane >> 4);
      aofs[mf][km] = a_r * 64 + ((b ^ (a_r & 7)) << 3);
    }
  }

  // prologue: load tile 0, stage into buf0
  float4 xa[8];
  s16x8 bfrag[4][2];
#pragma unroll
  for (int j = 0; j < 8; ++j)
    xa[j] = *(const float4*)(X + (row0 + rbase + 16 * j) * 512 + k4 * 4);
#pragma unroll
  for (int nf = 0; nf < 4; ++nf)
#pragma unroll
    for (int km = 0; km < 2; ++km)
      bfrag[nf][km] = *(const s16x8*)(W1f + bofs[nf] + (km << 9));
#pragma unroll
  for (int j = 0; j < 8; ++j) {
    uint2 p;
    p.x = pk2(xa[j].x, xa[j].y);
    p.y = pk2(xa[j].z, xa[j].w);
    *(uint2*)(&Alds[0][(16 * j) * 64 + wofs]) = p;
  }
  __syncthreads();

#pragma unroll
  for (int it = 0; it < 8; ++it) {
    // (1) issue next-tile global loads (full MFMA window to land)
    float4 xa2[8];
    s16x8 bf2[4][2];
    if (it < 7) {
      const int kc2 = (it + 1) * 64;
#pragma unroll
      for (int j = 0; j < 8; ++j)
        xa2[j] = *(const float4*)(X + (row0 + rbase + 16 * j) * 512 + kc2 + k4 * 4);
#pragma unroll
      for (int nf = 0; nf < 4; ++nf)
#pragma unroll
        for (int km = 0; km < 2; ++km)
          bf2[nf][km] = *(const s16x8*)(W1f + bofs[nf] + (((it + 1) * 2 + km) << 9));
    }
    // (2) LDS->reg fragments of current tile
    s16x8 afrag[4][2];
#pragma unroll
    for (int mf = 0; mf < 4; ++mf)
#pragma unroll
      for (int km = 0; km < 2; ++km)
        afrag[mf][km] = *(const s16x8*)(&Alds[it & 1][aofs[mf][km]]);
    // (3) MFMA
#pragma unroll
    for (int km = 0; km < 2; ++km)
#pragma unroll
      for (int mf = 0; mf < 4; ++mf)
#pragma unroll
        for (int nf = 0; nf < 4; ++nf)
          acc[mf][nf] = __builtin_amdgcn_mfma_f32_16x16x32_bf16(
              afrag[mf][km], bfrag[nf][km], acc[mf][nf], 0, 0, 0);
    // (4) stage next tile into other buffer; (5) one barrier
    if (it < 7) {
#pragma unroll
      for (int j = 0; j < 8; ++j) {
        uint2 p;
        p.x = pk2(xa2[j].x, xa2[j].y);
        p.y = pk2(xa2[j].z, xa2[j].w);
        *(uint2*)(&Alds[(it + 1) & 1][(16 * j) * 64 + wofs]) = p;
      }
#pragma unroll
      for (int nf = 0; nf < 4; ++nf)
#pragma unroll
        for (int km = 0; km < 2; ++km) bfrag[nf][km] = bf2[nf][km];
    }
    __syncthreads();
  }

  // ---- epilogue: bias + BN stats from regs; coalesced H1 via LDS transpose.
  float bv[4]; int col[4];
#pragma unroll
  for (int nf = 0; nf < 4; ++nf) {
    col[nf] = wc * 64 + nf * 16 + (lane & 15);
    bv[nf] = b1[col[nf]];
  }
  float s[4] = {0.f, 0.f, 0.f, 0.f}, ss[4] = {0.f, 0.f, 0.f, 0.f};
  ushort_t* Elds = &Alds[0][0];    // 64 x 136 bf16 = 17.4 KB (< 32 KB)
#pragma unroll
  for (int h = 0; h < 2; ++h) {
    if (wr == h) {
#pragma unroll
      for (int mf = 0; mf < 4; ++mf) {
        int rl = mf * 16 + ((lane >> 4) << 2);
#pragma unroll
        for (int r = 0; r < 4; ++r) {
#pragma unroll
          for (int nf = 0; nf < 4; ++nf) {
            float hv = acc[mf][nf][r] + bv[nf];
            Elds[(rl + r) * 136 + col[nf]] = f2bf(hv);
            s[nf] += hv; ss[nf] += hv * hv;
          }
        }
      }
    }
    __syncthreads();
#pragma unroll
    for (int i = 0; i < 4; ++i) {
      int idx = tid + 256 * i;        // 0..1023
      int row = idx >> 4, seg = idx & 15;
      uint4 v = *(const uint4*)(Elds + row * 136 + seg * 8);
      *(uint4*)(H1 + (row0 + h * 64 + row) * 128 + seg * 8) = v;
    }
    __syncthreads();
  }
#pragma unroll
  for (int nf = 0; nf < 4; ++nf) {
    atomicAdd(&lsum[col[nf]], s[nf]);
    atomicAdd(&lssq[col[nf]], ss[nf]);
  }
  __syncthreads();
  if (tid < 128) {
    atomicAdd(&colsum[tid], lsum[tid]);
    atomicAdd(&colsumsq[tid], lssq[tid]);
  }
}

// ---------------------------------------------------------------------------
// BN params for encoder
// ---------------------------------------------------------------------------
__global__ void k_bn1(const float* __restrict__ colsum,
                      const float* __restrict__ colsumsq,
                      const float* __restrict__ g, const float* __restrict__ be,
                      float* __restrict__ scale, float* __restrict__ shift)
{
  int j = threadIdx.x;
  float mu = colsum[j] * (1.f / NROWS);
  float var = colsumsq[j] * (1.f / NROWS) - mu * mu;
  float sc = g[j] * rsqrtf(var + 1e-5f);
  scale[j] = sc;
  shift[j] = be[j] - mu * sc;
}

// ---------------------------------------------------------------------------
// K3: BN+ReLU -> Z = Hb@W2 (MFMA) -> dists Z@CBb^T (MFMA K=32) + argmin.
// 64 rows/block, 4 waves x 16 rows.  (FROZEN vs round 6 for attribution)
// ---------------------------------------------------------------------------
__global__ __launch_bounds__(256, 4) void k_encode(
    const ushort_t* __restrict__ H1, const float* __restrict__ scale1,
    const float* __restrict__ shift1, const ushort_t* __restrict__ W2t,
    const float* __restrict__ b2, const ushort_t* __restrict__ CBb,
    const float* __restrict__ cn, int* __restrict__ topics,
    int* __restrict__ counts, float* __restrict__ Zloss)
{
  __shared__ ushort_t Hb[64 * 128];
  __shared__ float Zt[64 * 33];
  __shared__ int hist[512];
  __shared__ float zsh;

  const int tid = threadIdx.x;
  const int lane = tid & 63;
  const int w = tid >> 6;
  const int lr = lane & 15;
  const int lk = lane >> 4;
  const int row0 = blockIdx.x * 64;

  hist[tid] = 0; hist[tid + 256] = 0;
  if (tid == 0) zsh = 0.f;

  {
    const int c8 = (tid & 15) * 8;
    const int rb = tid >> 4;
    float sc[8], sh[8];
    {
      float4 a = *(const float4*)(scale1 + c8);
      float4 b = *(const float4*)(scale1 + c8 + 4);
      sc[0]=a.x; sc[1]=a.y; sc[2]=a.z; sc[3]=a.w; sc[4]=b.x; sc[5]=b.y; sc[6]=b.z; sc[7]=b.w;
      float4 e = *(const float4*)(shift1 + c8);
      float4 f = *(const float4*)(shift1 + c8 + 4);
      sh[0]=e.x; sh[1]=e.y; sh[2]=e.z; sh[3]=e.w; sh[4]=f.x; sh[5]=f.y; sh[6]=f.z; sh[7]=f.w;
    }
#pragma unroll
    for (int j = 0; j < 4; ++j) {
      int r = rb + 16 * j;
      uint4 v = *(const uint4*)(H1 + (size_t)(row0 + r) * HDIM + c8);
      uint_t u[4] = {v.x, v.y, v.z, v.w};
      uint4 o;
      uint_t* op = (uint_t*)&o;
#pragma unroll
      for (int m = 0; m < 4; ++m) {
        float f0 = fmaxf(bflo(u[m]) * sc[2*m]   + sh[2*m],   0.f);
        float f1 = fmaxf(bfhi(u[m]) * sc[2*m+1] + sh[2*m+1], 0.f);
        op[m] = pk2(f0, f1);
      }
      *(uint4*)(Hb + r * 128 + ((((c8 >> 3) ^ (r & 7))) << 3)) = o;
    }
  }
  __syncthreads();

  float zn4[4];
  {
    s16x8 af[4];
#pragma unroll
    for (int kt = 0; kt < 4; ++kt) {
      int m = w * 16 + lr;
      int b = kt * 4 + lk;
      af[kt] = *(const s16x8*)(Hb + m * 128 + ((b ^ (m & 7)) << 3));
    }
    f32x4 zacc[2];
    zacc[0] = (f32x4)(0.f); zacc[1] = (f32x4)(0.f);
#pragma unroll
    for (int ct = 0; ct < 2; ++ct)
#pragma unroll
      for (int kt = 0; kt < 4; ++kt) {
        s16x8 bf = *(const s16x8*)(W2t + (ct * 16 + lr) * 128 + kt * 32 + lk * 8);
        zacc[ct] = __builtin_amdgcn_mfma_f32_16x16x32_bf16(af[kt], bf, zacc[ct], 0, 0, 0);
      }
    float bias0 = b2[lr], bias1 = b2[16 + lr];
    float s4[4];
#pragma unroll
    for (int r = 0; r < 4; ++r) {
      float z0 = zacc[0][r] + bias0;
      float z1 = zacc[1][r] + bias1;
      int row = w * 16 + lk * 4 + r;
      Zt[row * 33 + lr] = z0;
      Zt[row * 33 + 16 + lr] = z1;
      s4[r] = z0 * z0 + z1 * z1;
    }
#pragma unroll
    for (int m = 1; m < 16; m <<= 1) {
#pragma unroll
      for (int r = 0; r < 4; ++r) s4[r] += __shfl_xor(s4[r], m, 64);
    }
#pragma unroll
    for (int r = 0; r < 4; ++r) zn4[r] = s4[r];
  }
  __syncthreads();

  {
    s16x8 za;
    {
      const float* zp = Zt + (w * 16 + lr) * 33 + lk * 8;
      float4 q0 = *(const float4*)(zp);
      float4 q1 = *(const float4*)(zp + 4);
      union { s16x8 v; uint_t u[4]; } zu;
      zu.u[0] = pk2(q0.x, q0.y);
      zu.u[1] = pk2(q0.z, q0.w);
      zu.u[2] = pk2(q1.x, q1.y);
      zu.u[3] = pk2(q1.z, q1.w);
      za = zu.v;
    }
    float minv[4] = {3.4e38f, 3.4e38f, 3.4e38f, 3.4e38f};
    int mini[4] = {0, 0, 0, 0};
#pragma unroll 4
    for (int t = 0; t < 32; ++t) {
      const int c = t * 16 + lr;
      s16x8 cb = *(const s16x8*)(CBb + c * 32 + lk * 8);
      f32x4 dot = __builtin_amdgcn_mfma_f32_16x16x32_bf16(za, cb, (f32x4)(0.f), 0, 0, 0);
      float cnv = cn[c];
#pragma unroll
      for (int r = 0; r < 4; ++r) {
        float d = fmaf(-2.f, dot[r], cnv);
        if (d < minv[r]) { minv[r] = d; mini[r] = c; }
      }
    }
#pragma unroll
    for (int m = 1; m < 16; m <<= 1) {
#pragma unroll
      for (int r = 0; r < 4; ++r) {
        float ov = __shfl_xor(minv[r], m, 64);
        int   oi = __shfl_xor(mini[r], m, 64);
        if (ov < minv[r] || (ov == minv[r] && oi < mini[r])) { minv[r] = ov; mini[r] = oi; }
      }
    }
    if (lr == 0) {
      float part = 0.f;
#pragma unroll
      for (int r = 0; r < 4; ++r) {
        int row = row0 + w * 16 + lk * 4 + r;
        topics[row] = mini[r];
        atomicAdd(&hist[mini[r]], 1);
        part += minv[r] + zn4[r];
      }
      atomicAdd(&zsh, part);
    }
  }
  __syncthreads();
  {
    int h0 = hist[tid], h1 = hist[tid + 256];
    if (h0) atomicAdd(&counts[tid], h0);
    if (h1) atomicAdd(&counts[tid + 256], h1);
    if (tid == 0) atomicAdd(Zloss, zsh);
  }
}

// Decoder BN params from topic histogram (exact batch stats)
__global__ void k_bn2(const int* __restrict__ counts, const float* __restrict__ T,
    const float* __restrict__ g, const float* __restrict__ be,
    float* __restrict__ scale2, float* __restrict__ shift2)
{
  __shared__ float cw[512];
  int j = threadIdx.x;  // 128
  for (int i = j; i < 512; i += 128) cw[i] = (float)counts[i];
  __syncthreads();
  float s = 0.f, ss = 0.f;
  for (int k = 0; k < KCODES; ++k) {
    float t = T[k * HDIM + j];
    float c = cw[k];
    s += c * t; ss += c * t * t;
  }
  float mu = s * (1.f / NROWS);
  float var = ss * (1.f / NROWS) - mu * mu;
  float sc = g[j] * rsqrtf(var + 1e-5f);
  scale2[j] = sc;
  shift2[j] = be[j] - mu * sc;
}

// U = relu(bn(T)) @ dec_W2 + dec_b2   [512 x 512]
__global__ __launch_bounds__(256) void k_U(const float* __restrict__ T,
    const float* __restrict__ scale2, const float* __restrict__ shift2,
    const float* __restrict__ dW2, const float* __restrict__ db2,
    float* __restrict__ U)
{
  __shared__ float Tb[128];
  const int tid = threadIdx.x;
  const int k = blockIdx.x >> 1;
  const int c = (blockIdx.x & 1) * 256 + tid;
  if (tid < 128) Tb[tid] = fmaxf(T[k * HDIM + tid] * scale2[tid] + shift2[tid], 0.f);
  __syncthreads();
  float acc = db2[c];
#pragma unroll 8
  for (int j = 0; j < HDIM; ++j) acc += Tb[j] * dW2[j * 512 + c];
  U[(size_t)k * 512 + c] = acc;
}

// Reconstruction: R += sum_n ||U[topic[n]] - X[n]||^2
__global__ __launch_bounds__(256, 4) void k_recon(
    const float* __restrict__ X, const float* __restrict__ U,
    const int* __restrict__ topics, float* __restrict__ Rsum)
{
  __shared__ float bsum;
  const int tid = threadIdx.x;
  if (tid == 0) bsum = 0.f;
  __syncthreads();
  const int lane = tid & 63;
  const int wave = blockIdx.x * 4 + (tid >> 6);
  float acc = 0.f;
  for (int r = wave; r < NROWS; r += 4096) {
    const int t = topics[r];
    const float4* xr = (const float4*)(X + (size_t)r * DIN);
    const float4* ur = (const float4*)(U + (size_t)t * 512);
    float4 x0 = xr[lane],      u0 = ur[lane];
    float4 x1 = xr[lane + 64], u1 = ur[lane + 64];
    float d;
    d = x0.x - u0.x; acc += d * d;
    d = x0.y - u0.y; acc += d * d;
    d = x0.z - u0.z; acc += d * d;
    d = x0.w - u0.w; acc += d * d;
    d = x1.x - u1.x; acc += d * d;
    d = x1.y - u1.y; acc += d * d;
    d = x1.z - u1.z; acc += d * d;
    d = x1.w - u1.w; acc += d * d;
  }
#pragma unroll
  for (int off = 32; off > 0; off >>= 1) acc += __shfl_down(acc, off, 64);
  if (lane == 0) atomicAdd(&bsum, acc);
  __syncthreads();
  if (tid == 0) atomicAdd(Rsum, bsum);
}

__global__ void k_final(const float* __restrict__ Zloss,
                        const float* __restrict__ Rsum, float* __restrict__ out)
{
  out[0] = 2.f * Zloss[0] + sqrtf(Rsum[0]);
}

// ---------------------------------------------------------------------------
// Workspace layout (bytes):
//   0         H1 bf16            [N*128]      33,554,432
//   33554432  topics int32       [N]             524,288
//   34078720  accumulators (zeroed by k_prep, 4 KB)
//   34082816  scale1[128]+shift1[128]
//   34083840  cn[512] f32
//   34085888  T[512*128] f32                   262,144
//   34348032  scale2[128]+shift2[128]
//   34349056  U[512*512] f32                 1,048,576  (W1f bf16 aliases; disjoint lifetime)
//   35397632  W2t bf16 [32][128]
//   35405824  CBb bf16 [512][32]
// ---------------------------------------------------------------------------
extern "C" void kernel_launch(void* const* d_in, const int* in_sizes, int n_in,
                              void* d_out, int out_size, void* d_ws, size_t ws_size,
                              hipStream_t stream) {
  const float* X    = (const float*)d_in[0];
  const float* eW1  = (const float*)d_in[1];
  const float* eb1  = (const float*)d_in[2];
  const float* eg1  = (const float*)d_in[3];
  const float* ebe1 = (const float*)d_in[4];
  const float* eW2  = (const float*)d_in[5];
  const float* eb2  = (const float*)d_in[6];
  const float* CB   = (const float*)d_in[7];
  const float* dW1  = (const float*)d_in[8];
  const float* db1  = (const float*)d_in[9];
  const float* dg1  = (const float*)d_in[10];
  const float* dbe1 = (const float*)d_in[11];
  const float* dW2  = (const float*)d_in[12];
  const float* db2  = (const float*)d_in[13];
  float* out = (float*)d_out;

  char* wsb = (char*)d_ws;
  ushort_t* H1    = (ushort_t*)wsb;
  int* topics     = (int*)(wsb + 33554432);
  float* colsum   = (float*)(wsb + 34078720);
  float* colsumsq = colsum + 128;
  int* counts     = (int*)(wsb + 34078720 + 1024);
  float* Zloss    = (float*)(wsb + 34078720 + 3072);
  float* Rsum     = Zloss + 1;
  float* scale1   = (float*)(wsb + 34082816);
  float* shift1   = scale1 + 128;
  float* cn       = (float*)(wsb + 34083840);
  float* T        = (float*)(wsb + 34085888);
  float* scale2   = (float*)(wsb + 34348032);
  float* shift2   = scale2 + 128;
  float* U        = (float*)(wsb + 34349056);
  ushort_t* W1f   = (ushort_t*)(wsb + 34349056);  // aliases U (disjoint lifetime)
  ushort_t* W2t   = (ushort_t*)(wsb + 35397632);
  ushort_t* CBb   = (ushort_t*)(wsb + 35405824);

  k_prep<<<256, 256, 0, stream>>>(eW1, eW2, CB, dW1, db1, W1f, W2t, CBb, cn, T,
                                  colsum);
  k_gemm1<<<NROWS / 128, 256, 0, stream>>>(X, W1f, eb1, H1, colsum, colsumsq);
  k_bn1<<<1, 128, 0, stream>>>(colsum, colsumsq, eg1, ebe1, scale1, shift1);
  k_encode<<<NROWS / 64, 256, 0, stream>>>(H1, scale1, shift1, W2t, eb2, CBb, cn,
                                           topics, counts, Zloss);
  k_bn2<<<1, 128, 0, stream>>>(counts, T, dg1, dbe1, scale2, shift2);
  k_U<<<KCODES * 2, 256, 0, stream>>>(T, scale2, shift2, dW2, db2, U);
  k_recon<<<1024, 256, 0, stream>>>(X, U, topics, Rsum);
  k_final<<<1, 1, 0, stream>>>(Zloss, Rsum, out);
}